// Round 1
// baseline (181.888 us; speedup 1.0000x reference)
//
#include <hip/hip_runtime.h>

// Problem dims (fixed)
#define B_  2
#define S_  1024
#define D_  1024
#define H_  16
#define DH_ 64

typedef __attribute__((ext_vector_type(8))) short bf16x8;
typedef __attribute__((ext_vector_type(4))) float f32x4;

__device__ __forceinline__ unsigned short f2bf(float f) {
  unsigned int u = __float_as_uint(f);
  u += 0x7fff + ((u >> 16) & 1);   // round-to-nearest-even
  return (unsigned short)(u >> 16);
}

__device__ __forceinline__ void gload_lds16(const void* g, void* l) {
  __builtin_amdgcn_global_load_lds(
      (const __attribute__((address_space(1))) unsigned int*)g,
      (__attribute__((address_space(3))) unsigned int*)l, 16, 0, 0);
}

// ---------------------------------------------------------------------------
// Kernel 1: fp32 -> bf16 convert for x, W_qkv, W_out
// ---------------------------------------------------------------------------
__global__ __launch_bounds__(256)
void cvt_kernel(const float4* __restrict__ x, const float4* __restrict__ wq,
                const float4* __restrict__ wo, unsigned short* __restrict__ xb,
                unsigned short* __restrict__ wqb, unsigned short* __restrict__ wob) {
  constexpr int n1 = (B_*S_*D_) / 4;       // 524288
  constexpr int n2 = (3*D_*D_) / 4;        // 786432
  constexpr int n3 = (D_*D_) / 4;          // 262144
  for (int i = blockIdx.x*blockDim.x + threadIdx.x; i < n1+n2+n3;
       i += gridDim.x*blockDim.x) {
    const float4* src; unsigned short* dst; int off;
    if (i < n1)          { src = x;  dst = xb;  off = i; }
    else if (i < n1+n2)  { src = wq; dst = wqb; off = i - n1; }
    else                 { src = wo; dst = wob; off = i - n1 - n2; }
    float4 v = src[off];
    ushort4 r;
    r.x = f2bf(v.x); r.y = f2bf(v.y); r.z = f2bf(v.z); r.w = f2bf(v.w);
    *(ushort4*)&dst[off*4] = r;
  }
}

// ---------------------------------------------------------------------------
// GEMM C = A @ Bw^T, A:[M,K] bf16 row-major, Bw:[N,K] bf16 row-major.
// m97 structure: 128x128 tile, BK=32, global_load_lds(16B), 4 waves (2x2),
// each wave 64x64 = 4x4 frags of 16x16x32 MFMA.
// EPI=0: store fp32 C.  EPI=1: scatter to Q/K [B,H,S,DH] and Vt [B,H,DH,S] bf16.
// ---------------------------------------------------------------------------
template<int M, int N, int K, int EPI>
__global__ __launch_bounds__(256)
void gemm_bt(const unsigned short* __restrict__ A, const unsigned short* __restrict__ Bw,
             float* __restrict__ C, unsigned short* __restrict__ Qb,
             unsigned short* __restrict__ Kb, unsigned short* __restrict__ Vtb) {
  constexpr int NBN = N / 128;
  __shared__ unsigned short As[128*32];
  __shared__ unsigned short Bs[128*32];
  const int tid = threadIdx.x;
  const int bid = blockIdx.x;
  const int mb = bid / NBN, nb = bid % NBN;
  const int wid = tid >> 6, lane = tid & 63;
  const int wr = wid >> 1, wc = wid & 1;
  const int lg = lane >> 4, lr = lane & 15;

  f32x4 acc[4][4] = {};

  const int mrow = mb*128, nrow = nb*128;
  const int srow = tid >> 2;       // 0..63
  const int scol = (tid & 3) * 8;  // 0,8,16,24

  for (int k0 = 0; k0 < K; k0 += 32) {
    #pragma unroll
    for (int h = 0; h < 2; ++h) {
      gload_lds16(A  + (size_t)(mrow + h*64 + srow)*K + k0 + scol, &As[(h*256 + tid)*8]);
      gload_lds16(Bw + (size_t)(nrow + h*64 + srow)*K + k0 + scol, &Bs[(h*256 + tid)*8]);
    }
    __syncthreads();   // emits vmcnt(0) drain before barrier
    bf16x8 af[4], bfr[4];
    #pragma unroll
    for (int t = 0; t < 4; ++t) {
      af[t]  = *(const bf16x8*)&As[(wr*64 + t*16 + lr)*32 + lg*8];
      bfr[t] = *(const bf16x8*)&Bs[(wc*64 + t*16 + lr)*32 + lg*8];
    }
    #pragma unroll
    for (int mt = 0; mt < 4; ++mt)
      #pragma unroll
      for (int nt = 0; nt < 4; ++nt)
        acc[mt][nt] = __builtin_amdgcn_mfma_f32_16x16x32_bf16(af[mt], bfr[nt], acc[mt][nt], 0, 0, 0);
    __syncthreads();
  }

  // Epilogue. C/D layout: row = lg*4 + i, col = lr  (verified m89/m91).
  #pragma unroll
  for (int mt = 0; mt < 4; ++mt) {
    const int m0 = mrow + wr*64 + mt*16 + lg*4;
    #pragma unroll
    for (int nt = 0; nt < 4; ++nt) {
      const int n = nrow + wc*64 + nt*16 + lr;
      f32x4 v = acc[mt][nt];
      if constexpr (EPI == 0) {
        #pragma unroll
        for (int i = 0; i < 4; ++i) C[(size_t)(m0 + i)*N + n] = v[i];
      } else {
        const int t3 = n >> 10, rem = n & 1023;
        const int hh = rem >> 6, dh = rem & 63;
        const int b = m0 >> 10, s0 = m0 & 1023;  // all 4 i share b (128 | 1024)
        if (t3 == 2) {
          // V transposed: Vt[b,h,dh,s]; 4 consecutive s -> one 8B store
          ushort4 pk;
          pk.x = f2bf(v[0]); pk.y = f2bf(v[1]); pk.z = f2bf(v[2]); pk.w = f2bf(v[3]);
          *(ushort4*)&Vtb[(size_t)((b*H_ + hh)*DH_ + dh)*S_ + s0] = pk;
        } else {
          unsigned short* dst = (t3 == 0) ? Qb : Kb;  // [b,h,s,dh]
          #pragma unroll
          for (int i = 0; i < 4; ++i)
            dst[(size_t)((b*H_ + hh)*S_ + s0 + i)*DH_ + dh] = f2bf(v[i]);
        }
      }
    }
  }
}

// ---------------------------------------------------------------------------
// Flash attention. Grid: B*H*(S/64)=512 blocks, 256 thr = 4 waves x 16 q-rows.
// K/V read straight from global (per-head K+V = 256KB, L2-resident).
// scores C-layout: row=q=lg*4+i, col=key=lr. P transposed to A-frag layout via
// small per-wave LDS tile (row stride 40 shorts = 80B: 16B-aligned, conflict-lite).
// ---------------------------------------------------------------------------
__global__ __launch_bounds__(256)
void attn_kernel(const unsigned short* __restrict__ Qb, const unsigned short* __restrict__ Kb,
                 const unsigned short* __restrict__ Vtb, unsigned short* __restrict__ AOb) {
  __shared__ unsigned short Pl[4][16*40];
  const int bid = blockIdx.x;
  const int qt = bid & 15;     // q-tile (64 rows)
  const int bh = bid >> 4;     // 0..31  (b*H + h)
  const int tid = threadIdx.x, wid = tid >> 6, lane = tid & 63;
  const int lg = lane >> 4, lr = lane & 15;
  const unsigned short* Q  = Qb  + (size_t)bh*S_*DH_;
  const unsigned short* Kp = Kb  + (size_t)bh*S_*DH_;
  const unsigned short* Vt = Vtb + (size_t)bh*DH_*S_;
  const int q0 = qt*64 + wid*16;

  // Hoisted Q A-fragments (A: row=lr, k=lg*8+t), DH=64 -> 2 k-steps
  bf16x8 qf0 = *(const bf16x8*)&Q[(q0 + lr)*DH_ + lg*8];
  bf16x8 qf1 = *(const bf16x8*)&Q[(q0 + lr)*DH_ + 32 + lg*8];

  float mrun[4], lrun[4], corr[4];
  f32x4 o[4] = {};
  #pragma unroll
  for (int i = 0; i < 4; ++i) { mrun[i] = -1e30f; lrun[i] = 0.f; }

  for (int j = 0; j < S_; j += 32) {
    f32x4 s0v = {}, s1v = {};
    bf16x8 kf;
    kf = *(const bf16x8*)&Kp[(j      + lr)*DH_ +      lg*8];
    s0v = __builtin_amdgcn_mfma_f32_16x16x32_bf16(qf0, kf, s0v, 0, 0, 0);
    kf = *(const bf16x8*)&Kp[(j      + lr)*DH_ + 32 + lg*8];
    s0v = __builtin_amdgcn_mfma_f32_16x16x32_bf16(qf1, kf, s0v, 0, 0, 0);
    kf = *(const bf16x8*)&Kp[(j + 16 + lr)*DH_ +      lg*8];
    s1v = __builtin_amdgcn_mfma_f32_16x16x32_bf16(qf0, kf, s1v, 0, 0, 0);
    kf = *(const bf16x8*)&Kp[(j + 16 + lr)*DH_ + 32 + lg*8];
    s1v = __builtin_amdgcn_mfma_f32_16x16x32_bf16(qf1, kf, s1v, 0, 0, 0);

    #pragma unroll
    for (int i = 0; i < 4; ++i) {
      float a  = s0v[i]*0.125f, c2 = s1v[i]*0.125f;
      float mx = fmaxf(a, c2);
      mx = fmaxf(mx, __shfl_xor(mx, 1));
      mx = fmaxf(mx, __shfl_xor(mx, 2));
      mx = fmaxf(mx, __shfl_xor(mx, 4));
      mx = fmaxf(mx, __shfl_xor(mx, 8));
      float mnew = fmaxf(mrun[i], mx);
      float cr = __expf(mrun[i] - mnew);
      float p0 = __expf(a  - mnew);
      float p1 = __expf(c2 - mnew);
      float rs = p0 + p1;
      rs += __shfl_xor(rs, 1);
      rs += __shfl_xor(rs, 2);
      rs += __shfl_xor(rs, 4);
      rs += __shfl_xor(rs, 8);
      lrun[i] = lrun[i]*cr + rs;
      mrun[i] = mnew;
      corr[i] = cr;
      Pl[wid][(lg*4 + i)*40 + lr]      = f2bf(p0);
      Pl[wid][(lg*4 + i)*40 + 16 + lr] = f2bf(p1);
    }
    #pragma unroll
    for (int d = 0; d < 4; ++d) {
      o[d][0] *= corr[0]; o[d][1] *= corr[1];
      o[d][2] *= corr[2]; o[d][3] *= corr[3];
    }
    asm volatile("s_waitcnt lgkmcnt(0)" ::: "memory");
    // P A-frag: row=lr, k=lg*8+t (wave-private LDS, in-order DS pipe)
    bf16x8 pa = *(const bf16x8*)&Pl[wid][lr*40 + lg*8];
    #pragma unroll
    for (int d = 0; d < 4; ++d) {
      // V B-frag: B[k=key][n=dh] = Vt[dh][key]: row = d*16+lr, 8 keys at lg*8
      bf16x8 vf = *(const bf16x8*)&Vt[(size_t)(d*16 + lr)*S_ + j + lg*8];
      o[d] = __builtin_amdgcn_mfma_f32_16x16x32_bf16(pa, vf, o[d], 0, 0, 0);
    }
  }

  const int b = bh >> 4, hh = bh & 15;
  #pragma unroll
  for (int d = 0; d < 4; ++d)
    #pragma unroll
    for (int i = 0; i < 4; ++i) {
      const int q = q0 + lg*4 + i;
      AOb[(size_t)(b*S_ + q)*D_ + hh*DH_ + d*16 + lr] = f2bf(o[d][i] / lrun[i]);
    }
}

// ---------------------------------------------------------------------------
extern "C" void kernel_launch(void* const* d_in, const int* in_sizes, int n_in,
                              void* d_out, int out_size, void* d_ws, size_t ws_size,
                              hipStream_t stream) {
  const float* x  = (const float*)d_in[0];   // [B,S,D]
  const float* wq = (const float*)d_in[1];   // [3D,D]
  const float* wo = (const float*)d_in[2];   // [D,D]
  float* out = (float*)d_out;                // [B,S,D] fp32

  unsigned short* w = (unsigned short*)d_ws;
  unsigned short* xb  = w;                   // 2097152 bf16
  unsigned short* wqb = xb  + 2097152;       // 3145728
  unsigned short* wob = wqb + 3145728;       // 1048576
  unsigned short* qb  = wob + 1048576;       // 2097152  Q [B,H,S,DH]
  unsigned short* kb  = qb  + 2097152;       // 2097152  K [B,H,S,DH]
  unsigned short* vtb = kb  + 2097152;       // 2097152  V^T [B,H,DH,S]
  unsigned short* aob = vtb + 2097152;       // 2097152  attn out [B,S,D]
  // total ws use: ~25.2 MB

  cvt_kernel<<<dim3(1024), dim3(256), 0, stream>>>(
      (const float4*)x, (const float4*)wq, (const float4*)wo, xb, wqb, wob);

  // QKV projection: M=2048 (B*S), N=3072 (3D), K=1024
  gemm_bt<2048, 3072, 1024, 1><<<dim3(16*24), dim3(256), 0, stream>>>(
      xb, wqb, nullptr, qb, kb, vtb);

  attn_kernel<<<dim3(512), dim3(256), 0, stream>>>(qb, kb, vtb, aob);

  // Output projection: M=2048, N=1024, K=1024
  gemm_bt<2048, 1024, 1024, 0><<<dim3(16*8), dim3(256), 0, stream>>>(
      aob, wob, out, nullptr, nullptr, nullptr);
}